// Round 1
// baseline (1120.352 us; speedup 1.0000x reference)
//
#include <hip/hip_runtime.h>
#include <hip/hip_bf16.h>

#define C_DIM 256
#define L_DIM 4096
#define H_DIM 512
#define KW    31
#define PADW  15

// ---------------------------------------------------------------------------
// prep: fold BN0 into expand weights; precompute per-channel affine params.
// W0[h,c] = w_expand[h,c] * inv0[c]
// bias0[h] = sum_c add0[c]*w_expand[h,c]   (folded into B1)
// A1=inv1, B1=bias0*inv1 + (b1 - m1*inv1)  -> h1 = relu(acc*A1 + B1)
// A2=inv2, B2=b2-m2*inv2                   -> h2 = relu(conv*A2 + B2)
// A3=inv3, B3=b3-m3*inv3                   -> out = acc*A3 + B3 + x
// ---------------------------------------------------------------------------
__global__ __launch_bounds__(256) void prep_kernel(
    const float* __restrict__ w_expand,
    const float* __restrict__ g0, const float* __restrict__ b0,
    const float* __restrict__ m0, const float* __restrict__ v0,
    const float* __restrict__ g1, const float* __restrict__ b1,
    const float* __restrict__ m1, const float* __restrict__ v1,
    const float* __restrict__ g2, const float* __restrict__ b2,
    const float* __restrict__ m2, const float* __restrict__ v2,
    const float* __restrict__ g3, const float* __restrict__ b3,
    const float* __restrict__ m3, const float* __restrict__ v3,
    float* __restrict__ W0, float* __restrict__ A1, float* __restrict__ B1,
    float* __restrict__ A2, float* __restrict__ B2,
    float* __restrict__ A3, float* __restrict__ B3)
{
    __shared__ float red[256];
    const int h = blockIdx.x;
    const int c = threadIdx.x;  // C_DIM == 256 == blockDim.x

    float inv0 = g0[c] / sqrtf(v0[c] + 1e-5f);
    float add0 = b0[c] - m0[c] * inv0;
    float w = w_expand[h * C_DIM + c];
    W0[h * C_DIM + c] = w * inv0;
    red[c] = add0 * w;
    __syncthreads();
    for (int s = 128; s > 0; s >>= 1) {
        if (c < s) red[c] += red[c + s];
        __syncthreads();
    }
    if (c == 0) {
        float bias0 = red[0];
        float inv1 = g1[h] / sqrtf(v1[h] + 1e-5f);
        A1[h] = inv1;
        B1[h] = bias0 * inv1 + (b1[h] - m1[h] * inv1);
        float inv2 = g2[h] / sqrtf(v2[h] + 1e-5f);
        A2[h] = inv2;
        B2[h] = b2[h] - m2[h] * inv2;
        if (h < C_DIM) {
            float inv3 = g3[h] / sqrtf(v3[h] + 1e-5f);
            A3[h] = inv3;
            B3[h] = b3[h] - m3[h] * inv3;
        }
    }
}

// ---------------------------------------------------------------------------
// expand: h1[b,h,l] = relu(A1[h] * (sum_c W0[h,c]*x[b,c,l]) + B1[h])
// 128x128 tile, BK=8, 256 threads, 8x8 per-thread micro-tile. fp32 FMA.
// ---------------------------------------------------------------------------
__global__ __launch_bounds__(256) void expand_kernel(
    const float* __restrict__ W0,   // [H, C]
    const float* __restrict__ xb,   // [nb, C, L] (chunk base)
    float* __restrict__ h1,         // [nb, H, L]
    const float* __restrict__ A1, const float* __restrict__ B1)
{
    __shared__ float As[8][128];
    __shared__ float Bs[8][128];
    const int bz = blockIdx.z;
    const float* Xb = xb + (size_t)bz * C_DIM * L_DIM;
    float* Ob = h1 + (size_t)bz * H_DIM * L_DIM;
    const int bm = blockIdx.y * 128;
    const int bn = blockIdx.x * 128;
    const int tid = threadIdx.x;
    const int tx = tid & 15, ty = tid >> 4;

    const int arow = tid >> 1;
    const int acol4 = (tid & 1) * 4;
    const int brow = tid >> 5;
    const int bcol4 = (tid & 31) * 4;

    float acc[8][8] = {};

    for (int k0 = 0; k0 < C_DIM; k0 += 8) {
        float4 av = *(const float4*)&W0[(size_t)(bm + arow) * C_DIM + k0 + acol4];
        float4 bv = *(const float4*)&Xb[(size_t)(k0 + brow) * L_DIM + bn + bcol4];
        As[acol4 + 0][arow] = av.x;
        As[acol4 + 1][arow] = av.y;
        As[acol4 + 2][arow] = av.z;
        As[acol4 + 3][arow] = av.w;
        *(float4*)&Bs[brow][bcol4] = bv;
        __syncthreads();
#pragma unroll
        for (int kk = 0; kk < 8; ++kk) {
            float4 a0 = *(const float4*)&As[kk][ty * 8];
            float4 a1 = *(const float4*)&As[kk][ty * 8 + 4];
            float4 b0 = *(const float4*)&Bs[kk][tx * 8];
            float4 b1 = *(const float4*)&Bs[kk][tx * 8 + 4];
            float a[8] = {a0.x, a0.y, a0.z, a0.w, a1.x, a1.y, a1.z, a1.w};
            float b[8] = {b0.x, b0.y, b0.z, b0.w, b1.x, b1.y, b1.z, b1.w};
#pragma unroll
            for (int i = 0; i < 8; ++i)
#pragma unroll
                for (int j = 0; j < 8; ++j) acc[i][j] += a[i] * b[j];
        }
        __syncthreads();
    }
#pragma unroll
    for (int i = 0; i < 8; ++i) {
        const int h = bm + ty * 8 + i;
        const float s = A1[h], t = B1[h];
        float4 o0, o1;
        float v;
        v = acc[i][0] * s + t; o0.x = v > 0.f ? v : 0.f;
        v = acc[i][1] * s + t; o0.y = v > 0.f ? v : 0.f;
        v = acc[i][2] * s + t; o0.z = v > 0.f ? v : 0.f;
        v = acc[i][3] * s + t; o0.w = v > 0.f ? v : 0.f;
        v = acc[i][4] * s + t; o1.x = v > 0.f ? v : 0.f;
        v = acc[i][5] * s + t; o1.y = v > 0.f ? v : 0.f;
        v = acc[i][6] * s + t; o1.z = v > 0.f ? v : 0.f;
        v = acc[i][7] * s + t; o1.w = v > 0.f ? v : 0.f;
        *(float4*)&Ob[(size_t)h * L_DIM + bn + tx * 8] = o0;
        *(float4*)&Ob[(size_t)h * L_DIM + bn + tx * 8 + 4] = o1;
    }
}

// ---------------------------------------------------------------------------
// depthwise conv K=31, pad 15, epilogue BN2+ReLU.
// One block per (1024-wide L segment, h, b). LDS-staged window.
// ---------------------------------------------------------------------------
__global__ __launch_bounds__(256) void dw_kernel(
    const float* __restrict__ h1, const float* __restrict__ w_dw,
    float* __restrict__ h2,
    const float* __restrict__ A2, const float* __restrict__ B2)
{
    __shared__ float buf[1024 + 2 * PADW];
    __shared__ float wsm[KW];
    const int h = blockIdx.y;
    const int bz = blockIdx.z;
    const size_t row = ((size_t)bz * H_DIM + h) * L_DIM;
    const int l0 = blockIdx.x * 1024;
    const int tid = threadIdx.x;

    if (tid < KW) wsm[tid] = w_dw[h * KW + tid];
    for (int i = tid; i < 1024 + 2 * PADW; i += 256) {
        int g = l0 - PADW + i;
        buf[i] = (g >= 0 && g < L_DIM) ? h1[row + g] : 0.f;
    }
    __syncthreads();
    const float s = A2[h], t = B2[h];
#pragma unroll
    for (int k = 0; k < 4; ++k) {
        const int local = tid + k * 256;
        float o = 0.f;
#pragma unroll
        for (int u = 0; u < KW; ++u) o += buf[local + u] * wsm[u];
        float v = o * s + t;
        h2[row + l0 + local] = v > 0.f ? v : 0.f;
    }
}

// ---------------------------------------------------------------------------
// project: out[b,c,l] = A3[c]*(sum_h Wp[c,h]*h2[b,h,l]) + B3[c] + x[b,c,l]
// ---------------------------------------------------------------------------
__global__ __launch_bounds__(256) void project_kernel(
    const float* __restrict__ Wp,   // [C, H]
    const float* __restrict__ h2,   // [nb, H, L]
    const float* __restrict__ xb,   // chunk x  (shortcut)
    float* __restrict__ outb,       // chunk out
    const float* __restrict__ A3, const float* __restrict__ B3)
{
    __shared__ float As[8][128];
    __shared__ float Bs[8][128];
    const int bz = blockIdx.z;
    const float* Hb = h2 + (size_t)bz * H_DIM * L_DIM;
    const float* Xb = xb + (size_t)bz * C_DIM * L_DIM;
    float* Ob = outb + (size_t)bz * C_DIM * L_DIM;
    const int bm = blockIdx.y * 128;
    const int bn = blockIdx.x * 128;
    const int tid = threadIdx.x;
    const int tx = tid & 15, ty = tid >> 4;

    const int arow = tid >> 1;
    const int acol4 = (tid & 1) * 4;
    const int brow = tid >> 5;
    const int bcol4 = (tid & 31) * 4;

    float acc[8][8] = {};

    for (int k0 = 0; k0 < H_DIM; k0 += 8) {
        float4 av = *(const float4*)&Wp[(size_t)(bm + arow) * H_DIM + k0 + acol4];
        float4 bv = *(const float4*)&Hb[(size_t)(k0 + brow) * L_DIM + bn + bcol4];
        As[acol4 + 0][arow] = av.x;
        As[acol4 + 1][arow] = av.y;
        As[acol4 + 2][arow] = av.z;
        As[acol4 + 3][arow] = av.w;
        *(float4*)&Bs[brow][bcol4] = bv;
        __syncthreads();
#pragma unroll
        for (int kk = 0; kk < 8; ++kk) {
            float4 a0 = *(const float4*)&As[kk][ty * 8];
            float4 a1 = *(const float4*)&As[kk][ty * 8 + 4];
            float4 b0 = *(const float4*)&Bs[kk][tx * 8];
            float4 b1 = *(const float4*)&Bs[kk][tx * 8 + 4];
            float a[8] = {a0.x, a0.y, a0.z, a0.w, a1.x, a1.y, a1.z, a1.w};
            float b[8] = {b0.x, b0.y, b0.z, b0.w, b1.x, b1.y, b1.z, b1.w};
#pragma unroll
            for (int i = 0; i < 8; ++i)
#pragma unroll
                for (int j = 0; j < 8; ++j) acc[i][j] += a[i] * b[j];
        }
        __syncthreads();
    }
#pragma unroll
    for (int i = 0; i < 8; ++i) {
        const int c = bm + ty * 8 + i;
        const float s = A3[c], t = B3[c];
        float4 x0 = *(const float4*)&Xb[(size_t)c * L_DIM + bn + tx * 8];
        float4 x1 = *(const float4*)&Xb[(size_t)c * L_DIM + bn + tx * 8 + 4];
        float4 o0, o1;
        o0.x = acc[i][0] * s + t + x0.x;
        o0.y = acc[i][1] * s + t + x0.y;
        o0.z = acc[i][2] * s + t + x0.z;
        o0.w = acc[i][3] * s + t + x0.w;
        o1.x = acc[i][4] * s + t + x1.x;
        o1.y = acc[i][5] * s + t + x1.y;
        o1.z = acc[i][6] * s + t + x1.z;
        o1.w = acc[i][7] * s + t + x1.w;
        *(float4*)&Ob[(size_t)c * L_DIM + bn + tx * 8] = o0;
        *(float4*)&Ob[(size_t)c * L_DIM + bn + tx * 8 + 4] = o1;
    }
}

extern "C" void kernel_launch(void* const* d_in, const int* in_sizes, int n_in,
                              void* d_out, int out_size, void* d_ws, size_t ws_size,
                              hipStream_t stream) {
    const float* x        = (const float*)d_in[0];
    const float* w_expand = (const float*)d_in[1];
    const float* w_dw     = (const float*)d_in[2];
    const float* w_proj   = (const float*)d_in[3];
    const float* g0 = (const float*)d_in[4],  *b0 = (const float*)d_in[5];
    const float* m0 = (const float*)d_in[6],  *v0 = (const float*)d_in[7];
    const float* g1 = (const float*)d_in[8],  *b1 = (const float*)d_in[9];
    const float* m1 = (const float*)d_in[10], *v1 = (const float*)d_in[11];
    const float* g2 = (const float*)d_in[12], *b2 = (const float*)d_in[13];
    const float* m2 = (const float*)d_in[14], *v2 = (const float*)d_in[15];
    const float* g3 = (const float*)d_in[16], *b3 = (const float*)d_in[17];
    const float* m3 = (const float*)d_in[18], *v3 = (const float*)d_in[19];
    float* out = (float*)d_out;

    const int B = in_sizes[0] / (C_DIM * L_DIM);  // 32

    float* ws = (float*)d_ws;
    size_t off = 0;
    float* W0 = ws + off; off += (size_t)H_DIM * C_DIM;
    float* A1 = ws + off; off += H_DIM;
    float* B1 = ws + off; off += H_DIM;
    float* A2 = ws + off; off += H_DIM;
    float* B2 = ws + off; off += H_DIM;
    float* A3 = ws + off; off += C_DIM;
    float* B3 = ws + off; off += C_DIM;
    off = (off + 255) & ~(size_t)255;

    // pick largest batch chunk that fits the workspace (16 MB per batch elem)
    const size_t per_b = 2 * (size_t)H_DIM * L_DIM;  // floats for h1+h2 per b
    int nb = 1;
    const int cands[5] = {32, 16, 8, 4, 2};
    for (int i = 0; i < 5; ++i) {
        if (B % cands[i]) continue;
        if ((off + per_b * cands[i]) * sizeof(float) <= ws_size) { nb = cands[i]; break; }
    }
    float* h1 = ws + off;
    float* h2 = h1 + (size_t)nb * H_DIM * L_DIM;

    prep_kernel<<<H_DIM, 256, 0, stream>>>(
        w_expand, g0, b0, m0, v0, g1, b1, m1, v1, g2, b2, m2, v2,
        g3, b3, m3, v3, W0, A1, B1, A2, B2, A3, B3);

    for (int cs = 0; cs < B; cs += nb) {
        const float* xb = x + (size_t)cs * C_DIM * L_DIM;
        float* ob = out + (size_t)cs * C_DIM * L_DIM;
        expand_kernel<<<dim3(L_DIM / 128, H_DIM / 128, nb), 256, 0, stream>>>(
            W0, xb, h1, A1, B1);
        dw_kernel<<<dim3(L_DIM / 1024, H_DIM, nb), 256, 0, stream>>>(
            h1, w_dw, h2, A2, B2);
        project_kernel<<<dim3(L_DIM / 128, C_DIM / 128, nb), 256, 0, stream>>>(
            w_proj, h2, xb, ob, A3, B3);
    }
}

// Round 2
// 396.608 us; speedup vs baseline: 2.8248x; 2.8248x over previous
//
#include <hip/hip_runtime.h>
#include <hip/hip_bf16.h>

#define C_DIM 256
#define L_DIM 4096
#define H_DIM 512
#define KW    31
#define PADW  15

typedef unsigned short u16;
typedef unsigned int   u32;
typedef short bf16x8 __attribute__((ext_vector_type(8)));
typedef float f32x4  __attribute__((ext_vector_type(4)));

__device__ __forceinline__ u16 f2bf(float f) {
    u32 u = __float_as_uint(f);
    u32 r = (u + 0x7FFFu + ((u >> 16) & 1u)) >> 16;
    return (u16)r;
}
__device__ __forceinline__ float bf2f(u16 h) {
    return __uint_as_float(((u32)h) << 16);
}

typedef __attribute__((address_space(1))) const unsigned int gq_t;
typedef __attribute__((address_space(3))) unsigned int lq_t;
__device__ __forceinline__ void async16(void* lds, const void* g) {
    __builtin_amdgcn_global_load_lds((gq_t*)g, (lq_t*)lds, 16, 0, 0);
}

// ---------------------------------------------------------------------------
// prep: fold BN0 into expand weights (bf16), compute per-channel affines.
// ---------------------------------------------------------------------------
__global__ __launch_bounds__(256) void prep_kernel(
    const float* __restrict__ w_expand,
    const float* __restrict__ g0, const float* __restrict__ b0,
    const float* __restrict__ m0, const float* __restrict__ v0,
    const float* __restrict__ g1, const float* __restrict__ b1,
    const float* __restrict__ m1, const float* __restrict__ v1,
    const float* __restrict__ g2, const float* __restrict__ b2,
    const float* __restrict__ m2, const float* __restrict__ v2,
    const float* __restrict__ g3, const float* __restrict__ b3,
    const float* __restrict__ m3, const float* __restrict__ v3,
    u16* __restrict__ W0bf, float* __restrict__ A1, float* __restrict__ B1,
    float* __restrict__ A2, float* __restrict__ B2,
    float* __restrict__ A3, float* __restrict__ B3)
{
    __shared__ float red[256];
    const int h = blockIdx.x;
    const int c = threadIdx.x;

    float inv0 = g0[c] / sqrtf(v0[c] + 1e-5f);
    float add0 = b0[c] - m0[c] * inv0;
    float w = w_expand[h * C_DIM + c];
    W0bf[h * C_DIM + c] = f2bf(w * inv0);
    red[c] = add0 * w;
    __syncthreads();
    for (int s = 128; s > 0; s >>= 1) {
        if (c < s) red[c] += red[c + s];
        __syncthreads();
    }
    if (c == 0) {
        float bias0 = red[0];
        float inv1 = g1[h] / sqrtf(v1[h] + 1e-5f);
        A1[h] = inv1;
        B1[h] = bias0 * inv1 + (b1[h] - m1[h] * inv1);
        float inv2 = g2[h] / sqrtf(v2[h] + 1e-5f);
        A2[h] = inv2;
        B2[h] = b2[h] - m2[h] * inv2;
        if (h < C_DIM) {
            float inv3 = g3[h] / sqrtf(v3[h] + 1e-5f);
            A3[h] = inv3;
            B3[h] = b3[h] - m3[h] * inv3;
        }
    }
}

__global__ __launch_bounds__(256) void convw_kernel(
    const float* __restrict__ w, u16* __restrict__ o, int n)
{
    int i = blockIdx.x * 256 + threadIdx.x;
    if (i < n) o[i] = f2bf(w[i]);
}

// ---------------------------------------------------------------------------
// convx: x fp32 [C][L] -> xT bf16 [L][C]  (per batch, LDS tile transpose)
// ---------------------------------------------------------------------------
__global__ __launch_bounds__(256) void convx_kernel(
    const float* __restrict__ x, u16* __restrict__ xT)
{
    __shared__ u16 t_s[64][68];
    const int b = blockIdx.z, c0 = blockIdx.y * 64, l0 = blockIdx.x * 64;
    const int tid = threadIdx.x;
    const float* xb = x + (size_t)b * C_DIM * L_DIM;
    {
        const int cl = tid >> 2, lg = (tid & 3) * 16;
        const float* src = xb + (size_t)(c0 + cl) * L_DIM + l0 + lg;
#pragma unroll
        for (int j = 0; j < 16; j += 4) {
            float4 v = *(const float4*)(src + j);
            ushort4 o;
            o.x = f2bf(v.x); o.y = f2bf(v.y); o.z = f2bf(v.z); o.w = f2bf(v.w);
            *(ushort4*)&t_s[cl][lg + j] = o;
        }
    }
    __syncthreads();
    {
        const int ll = tid >> 2, cg = (tid & 3) * 16;
        u32 w0[4], w1[4];
#pragma unroll
        for (int j = 0; j < 4; ++j) {
            w0[j] = (u32)t_s[cg + 2*j][ll] | ((u32)t_s[cg + 2*j + 1][ll] << 16);
            w1[j] = (u32)t_s[cg + 8 + 2*j][ll] | ((u32)t_s[cg + 9 + 2*j][ll] << 16);
        }
        u16* dst = xT + ((size_t)b * L_DIM + l0 + ll) * C_DIM + c0 + cg;
        uint4 o0; o0.x = w0[0]; o0.y = w0[1]; o0.z = w0[2]; o0.w = w0[3];
        uint4 o1; o1.x = w1[0]; o1.y = w1[1]; o1.z = w1[2]; o1.w = w1[3];
        *(uint4*)(dst)     = o0;
        *(uint4*)(dst + 8) = o1;
    }
}

// ---------------------------------------------------------------------------
// gemm_bt: D = A[M][K] * BT[N][K]^T, bf16 MFMA 16x16x32, 128x128 tile, BK=64
// EPI 0: Out = bf16 h1, v = relu(acc*Sa[row] + Sb[row])
// EPI 1: Out = fp32 out, v = acc*Sa[row] + Sb[row] + Xs[row][col]
// ---------------------------------------------------------------------------
template<int KDIM, int EPI>
__global__ __launch_bounds__(256) void gemm_bt_kernel(
    const u16* __restrict__ A,    // [M][KDIM] bf16
    const u16* __restrict__ BT,   // per b: [L_DIM][KDIM] bf16
    void* __restrict__ Out,
    const float* __restrict__ Sa, const float* __restrict__ Sb,
    const float* __restrict__ Xs)
{
    __shared__ short Asm[128 * 64];
    __shared__ short Bsm[128 * 64];
    const int b = blockIdx.z;
    const int bm = blockIdx.y * 128;
    const int bn = blockIdx.x * 128;
    const int tid = threadIdx.x;
    const int wave = tid >> 6, lane = tid & 63;
    const int wr = wave >> 1, wc = wave & 1;
    const int l15 = lane & 15, kg = lane >> 4;

    const u16* Bb = BT + (size_t)b * L_DIM * KDIM;

    const int srow = wave * 32 + (lane >> 3);
    const int scol = (lane & 7) * 8;
    const u16* gA = A  + (size_t)(bm + srow) * KDIM + scol;
    const u16* gB = Bb + (size_t)(bn + srow) * KDIM + scol;
    short* lA = Asm + wave * 32 * 64;
    short* lB = Bsm + wave * 32 * 64;

    f32x4 acc[4][4] = {};

    for (int kt = 0; kt < KDIM / 64; ++kt) {
        __syncthreads();
#pragma unroll
        for (int j = 0; j < 4; ++j) {
            async16(lA + j * 8 * 64, gA + (size_t)j * 8 * KDIM);
            async16(lB + j * 8 * 64, gB + (size_t)j * 8 * KDIM);
        }
        gA += 64; gB += 64;
        __syncthreads();
#pragma unroll
        for (int ks = 0; ks < 2; ++ks) {
            bf16x8 af[4], bf[4];
#pragma unroll
            for (int m = 0; m < 4; ++m)
                af[m] = *(const bf16x8*)&Asm[(wr * 64 + m * 16 + l15) * 64 + ks * 32 + kg * 8];
#pragma unroll
            for (int n = 0; n < 4; ++n)
                bf[n] = *(const bf16x8*)&Bsm[(wc * 64 + n * 16 + l15) * 64 + ks * 32 + kg * 8];
#pragma unroll
            for (int m = 0; m < 4; ++m)
#pragma unroll
                for (int n = 0; n < 4; ++n)
                    acc[m][n] = __builtin_amdgcn_mfma_f32_16x16x32_bf16(
                        af[m], bf[n], acc[m][n], 0, 0, 0);
        }
    }

    const int orow0 = bm + wr * 64;
    const int ocol = bn + wc * 64 + l15;
    if constexpr (EPI == 0) {
        u16* O = (u16*)Out + (size_t)b * H_DIM * L_DIM;
#pragma unroll
        for (int m = 0; m < 4; ++m)
#pragma unroll
        for (int r = 0; r < 4; ++r) {
            const int row = orow0 + m * 16 + kg * 4 + r;
            const float s = Sa[row], t = Sb[row];
#pragma unroll
            for (int n = 0; n < 4; ++n) {
                float v = acc[m][n][r] * s + t;
                v = v > 0.f ? v : 0.f;
                O[(size_t)row * L_DIM + ocol + n * 16] = f2bf(v);
            }
        }
    } else {
        float* O = (float*)Out + (size_t)b * C_DIM * L_DIM;
        const float* X = Xs + (size_t)b * C_DIM * L_DIM;
#pragma unroll
        for (int m = 0; m < 4; ++m)
#pragma unroll
        for (int r = 0; r < 4; ++r) {
            const int row = orow0 + m * 16 + kg * 4 + r;
            const float s = Sa[row], t = Sb[row];
#pragma unroll
            for (int n = 0; n < 4; ++n) {
                float v = acc[m][n][r] * s + t + X[(size_t)row * L_DIM + ocol + n * 16];
                O[(size_t)row * L_DIM + ocol + n * 16] = v;
            }
        }
    }
}

// ---------------------------------------------------------------------------
// dw: depthwise conv K=31 on h1 [H][L] bf16 -> h2T [L][H] bf16, BN2+ReLU.
// Tile: 32 h x 256 l, transposed write staged via LDS.
// ---------------------------------------------------------------------------
__global__ __launch_bounds__(256) void dw_kernel(
    const u16* __restrict__ h1, const float* __restrict__ w_dw,
    u16* __restrict__ h2T,
    const float* __restrict__ A2, const float* __restrict__ B2)
{
    __shared__ u16  in_s[32][290];
    __shared__ float wt_s[32 * 31];
    __shared__ u16  out_s[256][40];
    const int b = blockIdx.z, h0 = blockIdx.y * 32, l0 = blockIdx.x * 256;
    const int tid = threadIdx.x;
    const u16* hb = h1 + (size_t)b * H_DIM * L_DIM;

    for (int idx = tid; idx < 32 * 31; idx += 256)
        wt_s[idx] = w_dw[(h0 + idx / 31) * 31 + idx % 31];

    for (int idx = tid; idx < 32 * 36; idx += 256) {
        const int r = idx / 36, g = idx % 36;
        const int bl = l0 - 16 + g * 8;
        const u16* src = hb + (size_t)(h0 + r) * L_DIM + bl;
        u16 t0, t1, t2, t3, t4, t5, t6, t7;
        if (bl >= 0 && bl + 8 <= L_DIM) {
            ushort4 a = *(const ushort4*)(src);
            ushort4 c = *(const ushort4*)(src + 4);
            t0 = a.x; t1 = a.y; t2 = a.z; t3 = a.w;
            t4 = c.x; t5 = c.y; t6 = c.z; t7 = c.w;
        } else {
            t0 = (bl + 0 >= 0 && bl + 0 < L_DIM) ? src[0] : (u16)0;
            t1 = (bl + 1 >= 0 && bl + 1 < L_DIM) ? src[1] : (u16)0;
            t2 = (bl + 2 >= 0 && bl + 2 < L_DIM) ? src[2] : (u16)0;
            t3 = (bl + 3 >= 0 && bl + 3 < L_DIM) ? src[3] : (u16)0;
            t4 = (bl + 4 >= 0 && bl + 4 < L_DIM) ? src[4] : (u16)0;
            t5 = (bl + 5 >= 0 && bl + 5 < L_DIM) ? src[5] : (u16)0;
            t6 = (bl + 6 >= 0 && bl + 6 < L_DIM) ? src[6] : (u16)0;
            t7 = (bl + 7 >= 0 && bl + 7 < L_DIM) ? src[7] : (u16)0;
        }
        ushort2 p;
        p.x = t0; p.y = t1; *(ushort2*)&in_s[r][g * 8 + 0] = p;
        p.x = t2; p.y = t3; *(ushort2*)&in_s[r][g * 8 + 2] = p;
        p.x = t4; p.y = t5; *(ushort2*)&in_s[r][g * 8 + 4] = p;
        p.x = t6; p.y = t7; *(ushort2*)&in_s[r][g * 8 + 6] = p;
    }
    __syncthreads();

    const int hl = tid & 31, lg = tid >> 5;
    const int h = h0 + hl;
    float wreg[KW];
#pragma unroll
    for (int u = 0; u < KW; ++u) wreg[u] = wt_s[hl * KW + u];
    const float s2 = A2[h], t2v = B2[h];

#pragma unroll
    for (int p = 0; p < 2; ++p) {
        const int ll0 = lg * 16 + p * 128;
        float win[48];
#pragma unroll
        for (int j = 0; j < 48; j += 2) {
            ushort2 u2 = *(const ushort2*)&in_s[hl][ll0 + j];
            win[j]     = bf2f(u2.x);
            win[j + 1] = bf2f(u2.y);
        }
        float acc[16] = {};
#pragma unroll
        for (int u = 0; u < KW; ++u)
#pragma unroll
            for (int i = 0; i < 16; ++i)
                acc[i] += win[i + 1 + u] * wreg[u];
#pragma unroll
        for (int i = 0; i < 16; ++i) {
            float v = acc[i] * s2 + t2v;
            v = v > 0.f ? v : 0.f;
            out_s[ll0 + i][hl] = f2bf(v);
        }
    }
    __syncthreads();

    u16* dst = h2T + ((size_t)b * L_DIM + l0 + tid) * H_DIM + h0;
    const uint4* s4 = (const uint4*)&out_s[tid][0];
    uint4 a0 = s4[0], a1 = s4[1], a2 = s4[2], a3 = s4[3];
    ((uint4*)dst)[0] = a0; ((uint4*)dst)[1] = a1;
    ((uint4*)dst)[2] = a2; ((uint4*)dst)[3] = a3;
}

extern "C" void kernel_launch(void* const* d_in, const int* in_sizes, int n_in,
                              void* d_out, int out_size, void* d_ws, size_t ws_size,
                              hipStream_t stream) {
    const float* x        = (const float*)d_in[0];
    const float* w_expand = (const float*)d_in[1];
    const float* w_dw     = (const float*)d_in[2];
    const float* w_proj   = (const float*)d_in[3];
    const float* g0 = (const float*)d_in[4],  *b0 = (const float*)d_in[5];
    const float* m0 = (const float*)d_in[6],  *v0 = (const float*)d_in[7];
    const float* g1 = (const float*)d_in[8],  *b1 = (const float*)d_in[9];
    const float* m1 = (const float*)d_in[10], *v1 = (const float*)d_in[11];
    const float* g2 = (const float*)d_in[12], *b2 = (const float*)d_in[13];
    const float* m2 = (const float*)d_in[14], *v2 = (const float*)d_in[15];
    const float* g3 = (const float*)d_in[16], *b3 = (const float*)d_in[17];
    const float* m3 = (const float*)d_in[18], *v3 = (const float*)d_in[19];
    float* out = (float*)d_out;

    const int B = in_sizes[0] / (C_DIM * L_DIM);

    char* base = (char*)d_ws;
    size_t off = 0;
    u16* W0bf = (u16*)(base + off); off += (size_t)H_DIM * C_DIM * 2;
    u16* Wpbf = (u16*)(base + off); off += (size_t)C_DIM * H_DIM * 2;
    float* A1p = (float*)(base + off); off += H_DIM * 4;
    float* B1p = (float*)(base + off); off += H_DIM * 4;
    float* A2p = (float*)(base + off); off += H_DIM * 4;
    float* B2p = (float*)(base + off); off += H_DIM * 4;
    float* A3p = (float*)(base + off); off += C_DIM * 4;
    float* B3p = (float*)(base + off); off += C_DIM * 4;
    off = (off + 255) & ~(size_t)255;

    const size_t per_b = ((size_t)L_DIM * C_DIM + 2 * (size_t)H_DIM * L_DIM) * 2;
    int nb = 1;
    const int cands[6] = {32, 16, 8, 4, 2, 1};
    for (int i = 0; i < 6; ++i) {
        if (B % cands[i]) continue;
        if (off + per_b * cands[i] <= ws_size) { nb = cands[i]; break; }
    }
    u16* xT  = (u16*)(base + off);
    u16* h1  = xT + (size_t)nb * L_DIM * C_DIM;
    u16* h2T = h1 + (size_t)nb * H_DIM * L_DIM;

    prep_kernel<<<H_DIM, 256, 0, stream>>>(
        w_expand, g0, b0, m0, v0, g1, b1, m1, v1, g2, b2, m2, v2,
        g3, b3, m3, v3, W0bf, A1p, B1p, A2p, B2p, A3p, B3p);
    convw_kernel<<<(C_DIM * H_DIM + 255) / 256, 256, 0, stream>>>(
        w_proj, Wpbf, C_DIM * H_DIM);

    for (int cs = 0; cs < B; cs += nb) {
        const float* xb = x + (size_t)cs * C_DIM * L_DIM;
        float* ob = out + (size_t)cs * C_DIM * L_DIM;
        convx_kernel<<<dim3(L_DIM / 64, C_DIM / 64, nb), 256, 0, stream>>>(xb, xT);
        gemm_bt_kernel<C_DIM, 0><<<dim3(L_DIM / 128, H_DIM / 128, nb), 256, 0, stream>>>(
            W0bf, xT, h1, A1p, B1p, nullptr);
        dw_kernel<<<dim3(L_DIM / 256, H_DIM / 32, nb), 256, 0, stream>>>(
            h1, w_dw, h2T, A2p, B2p);
        gemm_bt_kernel<H_DIM, 1><<<dim3(L_DIM / 128, C_DIM / 128, nb), 256, 0, stream>>>(
            Wpbf, h2T, ob, A3p, B3p, xb);
    }
}